// Round 15
// baseline (5079.095 us; speedup 1.0000x reference)
//
#include <hip/hip_runtime.h>
#include <hip/hip_bf16.h>

// StackedMatchLSTM on MI355X — r14 protocol + batch-pair phase sharing.
// B=32, TP=512, TQ=64, DP=DQ=H=AH=256, NL=2.
// Scan: 128 WGs (8 slices x 16 pairs) x 512 threads. WG (pair,j) serves
// batches {pair, pair+16} with slice j (32 att cols + 128 gate cols).
// Both batches march through IDENTICAL lock-stepped phases within each step
// (no cross-step pipelining — that was r10-12's failure). Exchange: r14's
// seq-stamped 8B relaxed agent atomics; both batches' spin-loads issue
// concurrently (spinload2) so the pair shares each LLC round trip, and the
// 9 barriers/step are amortized over two batch-steps. Weights LDS-resident
// (shared across the pair), consumption-ordered layouts (0 bank conflicts).

#define NB 32
#define TPL 512
#define TQL 64
#define DD 256      // DP = DQ = H = AH
#define H4 1024     // 4*H
#define NC 1280     // AH + 4H
#define NS 8        // slices per batch
#define SC 160      // xpl cols per slice = 32 att + 128 gate
#define GC 128      // gate cols per slice

typedef unsigned long long u64;

__device__ __forceinline__ float fast_tanh(float x) {
  float xc = fminf(fmaxf(x, -9.f), 9.f);
  float e = __expf(2.f * xc);
  return (e - 1.f) * __builtin_amdgcn_rcpf(e + 1.f);
}
__device__ __forceinline__ float fast_sigmoid(float x) {
  return __builtin_amdgcn_rcpf(1.f + __expf(-x));
}
__device__ __forceinline__ float bflo(unsigned int w) { return __uint_as_float(w << 16); }
__device__ __forceinline__ float bfhi(unsigned int w) { return __uint_as_float(w & 0xffff0000u); }
__device__ __forceinline__ unsigned int packbf(float a, float b) {
  unsigned int lo = __hip_bfloat16_raw(__float2bfloat16(a)).x;
  unsigned int hi = __hip_bfloat16_raw(__float2bfloat16(b)).x;
  return lo | (hi << 16);
}

// ---- seq-stamped payload exchange (relaxed agent atomics, LLC-coherent) -----
__device__ __forceinline__ u64 aload64(const u64* p) {
  return __hip_atomic_load(p, __ATOMIC_RELAXED, __HIP_MEMORY_SCOPE_AGENT);
}
__device__ __forceinline__ void astore64(u64* p, u64 v) {
  __hip_atomic_store(p, v, __ATOMIC_RELAXED, __HIP_MEMORY_SCOPE_AGENT);
}
__device__ __forceinline__ u64 packsv(float val, unsigned int seq) {
  return ((u64)seq << 32) | (u64)__float_as_uint(val);
}
// two concurrent self-validating spin-loads (both in flight -> ~1 LLC RT)
__device__ __forceinline__ void spinload2(const u64* p0, const u64* p1,
                                          unsigned int seq,
                                          float* v0, float* v1) {
  u64 a = aload64(p0);
  u64 b = aload64(p1);
  int guard = 0;
  while (((unsigned int)(a >> 32) != seq) || ((unsigned int)(b >> 32) != seq)) {
    __builtin_amdgcn_s_sleep(1);
    if ((unsigned int)(a >> 32) != seq) a = aload64(p0);
    if ((unsigned int)(b >> 32) != seq) b = aload64(p1);
    if (++guard > (1 << 24)) break;   // bail instead of hanging the harness
  }
  *v0 = __uint_as_float((unsigned int)a);
  *v1 = __uint_as_float((unsigned int)b);
}

// permuted xpl cols: slice-major blocks of 160: 32 att | f|i|o|g x32
__device__ __forceinline__ int perm_col(int c) {
  if (c < DD) return (c >> 5) * SC + (c & 31);
  int cc = c - DD;
  int g = cc >> 8;          // 0..3 = f,i,o,g
  int m = cc & 255;         // h-elem
  return (m >> 5) * SC + 32 + (g << 5) + (m & 31);
}

// ---- weight prep ------------------------------------------------------------
__global__ __launch_bounds__(256) void pack_weights(
    const float* __restrict__ Wp, const float* __restrict__ Wq,
    const float* __restrict__ Wl,
    float* __restrict__ wx, float* __restrict__ wqv)
{
  int d = blockIdx.y;
  int idx = blockIdx.x * 256 + threadIdx.x;
  if (idx >= DD * NC) return;
  int k = idx / NC, j = idx % NC;
  int o = d * DD * NC + idx;
  const float* Wld = Wl + (size_t)d * 768 * H4;
  if (j < DD) {
    int s = d * DD * DD + k * DD + j;
    wx[o] = Wp[s]; wqv[o] = Wq[s];
  } else {
    int c = j - DD;
    wx[o]  = Wld[(size_t)k * H4 + c];
    wqv[o] = Wld[(size_t)(DD + k) * H4 + c];
  }
}

// attl, consumption order: [(d*8+j)][i(4)][slot(512)], slot = ak*32 + acol.
// uint2 = k's {4kq..4kq+3} of col (32j+acol), kq = ak*4 + i.
__global__ __launch_bounds__(256) void pack_attl(
    const float* __restrict__ Wr, uint2* __restrict__ attl)
{
  int idx = blockIdx.x * 256 + threadIdx.x;       // 2*8*4*512 = 32768
  if (idx >= 2 * NS * 4 * 512) return;
  int slot = idx & 511; int r = idx >> 9;
  int i = r & 3; r >>= 2;
  int j = r & 7; int d = r >> 3;
  int acol = slot & 31, ak = slot >> 5;
  int kq = ak * 4 + i;
  int col = (j << 5) + acol;
  float v[4];
  #pragma unroll
  for (int kr = 0; kr < 4; ++kr)
    v[kr] = Wr[((size_t)d * DD + kq * 4 + kr) * DD + col];
  attl[idx] = make_uint2(packbf(v[0], v[1]), packbf(v[2], v[3]));
}

// gatel, consumption order: [(d*8+j)][i(16)][slot(512)], slot: gcol=slot>>2,
// gq=slot&3. uint2 = k's {4kq..4kq+3} of gate col gcol, kq = i*4 + gq.
__global__ __launch_bounds__(256) void pack_gatel(
    const float* __restrict__ Wl, uint2* __restrict__ gatel)
{
  int idx = blockIdx.x * 256 + threadIdx.x;       // 2*8*16*512 = 131072
  if (idx >= 2 * NS * 16 * 512) return;
  int slot = idx & 511; int r = idx >> 9;
  int i = r & 15; r >>= 4;
  int j = r & 7; int d = r >> 3;
  int gcol = slot >> 2, gq = slot & 3;
  int kq = i * 4 + gq;
  int g = gcol >> 5, pos = gcol & 31;
  float v[4];
  #pragma unroll
  for (int kr = 0; kr < 4; ++kr) {
    int k = kq * 4 + kr;
    v[kr] = Wl[((size_t)d * 768 + 512 + k) * H4 + (g << 8) + (j << 5) + pos];
  }
  gatel[idx] = make_uint2(packbf(v[0], v[1]), packbf(v[2], v[3]));
}

// ---- C[M][1280] = A[M][256] @ B[256][1280], fp32 ----------------------------
template <bool PERM>
__global__ __launch_bounds__(256) void sgemm(
    const float* __restrict__ A, const float* __restrict__ Bm,
    float* __restrict__ C)
{
  __shared__ float As[16][65];
  __shared__ float Bs[16][64];
  int tid = threadIdx.x;
  int tx = tid & 15, ty = tid >> 4;
  int col0 = blockIdx.x * 64, row0 = blockIdx.y * 64;
  float acc[4][4] = {};
  for (int kt = 0; kt < DD; kt += 16) {
    #pragma unroll
    for (int i = 0; i < 4; ++i) {
      int e = tid + i * 256;
      As[e & 15][e >> 4] = A[(size_t)(row0 + (e >> 4)) * DD + kt + (e & 15)];
      Bs[e >> 6][e & 63] = Bm[(size_t)(kt + (e >> 6)) * NC + col0 + (e & 63)];
    }
    __syncthreads();
    #pragma unroll
    for (int kk = 0; kk < 16; ++kk) {
      float a[4], bv[4];
      #pragma unroll
      for (int i = 0; i < 4; ++i) a[i] = As[kk][ty * 4 + i];
      #pragma unroll
      for (int jj = 0; jj < 4; ++jj) bv[jj] = Bs[kk][tx * 4 + jj];
      #pragma unroll
      for (int i = 0; i < 4; ++i)
        #pragma unroll
        for (int jj = 0; jj < 4; ++jj)
          acc[i][jj] = fmaf(a[i], bv[jj], acc[i][jj]);
    }
    __syncthreads();
  }
  #pragma unroll
  for (int i = 0; i < 4; ++i)
    #pragma unroll
    for (int jj = 0; jj < 4; ++jj) {
      int c = col0 + tx * 4 + jj;
      int cc = PERM ? perm_col(c) : c;
      C[(size_t)(row0 + ty * 4 + i) * NC + cc] = acc[i][jj];
    }
}

// ---- scan: 128 WGs x 512 threads, two batches per WG (lock-stepped) ---------
__global__ __launch_bounds__(512, 1) void scan(
    const float* __restrict__ xpl,    // [NB*TP][NC] permuted cols
    const float* __restrict__ qv,     // [NB*TQ][NC] plain (this layer)
    const uint2* __restrict__ attl,   // this layer's [8][4][512]
    const uint2* __restrict__ gatel,  // this layer's [8][16][512]
    const float* __restrict__ wa,     // [256]
    const float* __restrict__ bias_f,
    const float* __restrict__ bias_iog,
    const float* __restrict__ mask_p,
    const float* __restrict__ mask_q,
    u64* __restrict__ xch_s,          // [NB][NS][64] seq-stamped scores
    u64* __restrict__ xch_h,          // [NB][256]  seq-stamped h
    float* __restrict__ out,          // [NB*TP][256]
    int lbase)                        // layer*TPL
{
  const int wgid = blockIdx.x;
  const int j = wgid & 7, pair = wgid >> 3;     // pair 0..15
  const int tid = threadIdx.x;
  const int lane = tid & 63;
  const int bS0 = pair, bS1 = pair + 16;

  __shared__ uint2 wg_l[16][512];        // 64 KB gate weights (shared by pair)
  __shared__ uint2 wat_l[4][512];        // 16 KB att weights (shared)
  __shared__ unsigned int vl_l[2][8][512]; // 32 KB Vl bf16 pairs (per batch)
  __shared__ float qT[2][32][65];        // 16.6 KB qWq^T (per batch)
  __shared__ __align__(16) float h_lds[2][DD];
  __shared__ float xsl[2][SC];
  __shared__ float hw_att[2][32], waa[32], c_dummy;
  __shared__ float att_part[2][16][33];
  __shared__ float sc_part[2][8][TQL];
  __shared__ float al_s[2][TQL];
  __shared__ float pre_s[2][GC], bias_s[GC];

  const float* qvb[2] = { qv + (size_t)bS0 * TQL * NC,
                          qv + (size_t)bS1 * TQL * NC };
  u64* xsc[2] = { xch_s + bS0 * (NS * TQL), xch_s + bS1 * (NS * TQL) };
  u64* xh[2]  = { xch_h + bS0 * DD,         xch_h + bS1 * DD };

  // ---- one-time preload: weights (shared) + per-batch activations
  {
    const uint2* gp = gatel + (size_t)j * 16 * 512;
    for (int i = tid; i < 16 * 512; i += 512) wg_l[i >> 9][i & 511] = gp[i];
    const uint2* ap = attl + (size_t)j * 4 * 512;
    for (int i = tid; i < 4 * 512; i += 512) wat_l[i >> 9][i & 511] = ap[i];
    #pragma unroll
    for (int s = 0; s < 2; ++s) {
      for (int i = tid; i < TQL * 32; i += 512) {
        int tq = i >> 5, a = i & 31;
        qT[s][a][tq] = qvb[s][(size_t)tq * NC + (j << 5) + a];
      }
      for (int f = tid; f < 8 * 512; f += 512) {
        int ii = f >> 9, slot = f & 511;
        int gcol = slot >> 2, gq = slot & 3;
        int tw = gq * 8 + ii;
        int g = gcol >> 5, m = (j << 5) + (gcol & 31);
        float v0 = qvb[s][(size_t)(2 * tw) * NC + DD + (g << 8) + m];
        float v1 = qvb[s][(size_t)(2 * tw + 1) * NC + DD + (g << 8) + m];
        vl_l[s][ii][slot] = packbf(v0, v1);
      }
    }
    if (tid < 32) waa[tid] = wa[(j << 5) + tid];
    if (tid < GC) {
      int g = tid >> 5, m = (j << 5) + (tid & 31);
      bias_s[tid] = (g == 0) ? bias_f[m] : bias_iog[((g - 1) << 8) + m];
    }
  }
  // softmax mask: waves 0/1 handle batches 0/1, lane = tq
  float mqv = (tid < 128) ? mask_q[((tid >> 6) ? bS1 : bS0) * TQL + lane] : 0.f;
  float cv = 0.f;                       // cell state: tid<64, s=lane>>5, e=lane&31
  __syncthreads();

  // role indices
  const int ak = tid >> 5;                        // att: 16-way k-split
  const int stq = tid & 63, ssub = tid >> 6;      // scores: 8 subs x 4 cols
  const int gcol = tid >> 2, gq = tid & 3;        // gate/pre: 4-way k/tq split

  for (int t = 0; t < TPL; ++t) {
    const float* xrA = xpl + ((size_t)bS0 * TPL + t) * NC + j * SC;
    const float* xrB = xpl + ((size_t)bS1 * TPL + t) * NC + j * SC;
    float xv = 0.f;
    if (tid < SC) xv = xrA[tid];
    else if (tid < 2 * SC) xv = xrB[tid - SC];
    float mtv = (tid < 64) ? mask_p[((lane >> 5) ? bS1 : bS0) * TPL + t] : 0.f;
    const unsigned int hseq = (unsigned int)(lbase + t);
    const unsigned int sseq = (unsigned int)(lbase + t + 1);

    __syncthreads();                   // B0: prev-step LDS reads done
    // ---- spin-load h[t] for BOTH batches (concurrent -> shared RT)
    if (tid < DD) {
      float hA = 0.f, hB = 0.f;
      if (t > 0) spinload2(xh[0] + tid, xh[1] + tid, hseq, &hA, &hB);
      h_lds[0][tid] = hA;
      h_lds[1][tid] = hB;
    }
    if (tid < SC) xsl[0][tid] = xv;
    else if (tid < 2 * SC) xsl[1][tid - SC] = xv;
    __syncthreads();                   // B1: h_lds, xsl ready

    // ---- att GEMV from LDS, both batches: 32 cols x 16-way k-split
    #pragma unroll
    for (int s = 0; s < 2; ++s) {
      float a0 = 0.f, a1 = 0.f;
      #pragma unroll
      for (int i = 0; i < 4; ++i) {
        int kq = ak * 4 + i;
        uint2 w = wat_l[i][tid];
        float4 h0 = *(const float4*)&h_lds[s][kq * 4];
        a0 = fmaf(h0.x, bflo(w.x), a0); a1 = fmaf(h0.y, bfhi(w.x), a1);
        a0 = fmaf(h0.z, bflo(w.y), a0); a1 = fmaf(h0.w, bfhi(w.y), a1);
      }
      att_part[s][ak][tid & 31] = a0 + a1;
    }
    __syncthreads();                   // B2
    if (tid < 64) {
      int s = tid >> 5, e = tid & 31;
      float sum = 0.f;
      #pragma unroll
      for (int i = 0; i < 16; ++i) sum += att_part[s][i][e];
      hw_att[s][e] = sum;
    }
    __syncthreads();                   // B3: hw_att ready

    // ---- scores, both batches: 64 tq x 8 subs (4 a each)
    #pragma unroll
    for (int s = 0; s < 2; ++s) {
      float p = 0.f;
      #pragma unroll
      for (int i = 0; i < 4; ++i) {
        int a = ssub * 4 + i;
        p = fmaf(fast_tanh(qT[s][a][stq] + xsl[s][a] + hw_att[s][a]),
                 waa[a], p);
      }
      sc_part[s][ssub][stq] = p;
    }
    __syncthreads();                   // B4
    // ---- publish score partials: wave 0 -> batch A, wave 1 -> batch B
    // (seq-stamped elements self-validate; no cross-wave ordering needed)
    if (tid < 128) {
      int s = tid >> 6;
      float sum = 0.f;
      #pragma unroll
      for (int q = 0; q < 8; ++q) sum += sc_part[s][q][lane];
      astore64(xsc[s] + (j << 6) + lane, packsv(sum, sseq));
    }

    // ---- gate GEMV from LDS, both batches (hides score flight)
    float hwgA, hwgB;
    #pragma unroll
    for (int s = 0; s < 2; ++s) {
      float g0 = 0.f, g1 = 0.f;
      #pragma unroll
      for (int i = 0; i < 16; ++i) {
        int kq = i * 4 + gq;                     // interleaved k-split
        uint2 w = wg_l[i][tid];
        float4 h0 = *(const float4*)&h_lds[s][kq * 4];
        g0 = fmaf(h0.x, bflo(w.x), g0); g1 = fmaf(h0.y, bfhi(w.x), g1);
        g0 = fmaf(h0.z, bflo(w.y), g0); g1 = fmaf(h0.w, bfhi(w.y), g1);
      }
      float hw = g0 + g1;
      hw += __shfl_xor(hw, 1);
      hw += __shfl_xor(hw, 2);         // all 4 partners hold full hw_gate[gcol]
      if (s == 0) hwgA = hw; else hwgB = hw;
    }

    // ---- spin-load score partials for BOTH batches (concurrent), softmax
    __syncthreads();                   // B5: publishers' sc_part reads done
    {
      float vA, vB;
      spinload2(xsc[0] + (ssub << 6) + stq, xsc[1] + (ssub << 6) + stq,
                sseq, &vA, &vB);
      sc_part[0][ssub][stq] = vA;
      sc_part[1][ssub][stq] = vB;
    }
    __syncthreads();                   // B6
    if (tid < 128) {
      int s = tid >> 6;
      float v = 0.f;
      #pragma unroll
      for (int q = 0; q < 8; ++q) v += sc_part[s][q][lane];
      v = (mqv > 0.f) ? v : -1e9f;
      float m = v;
      #pragma unroll
      for (int off = 32; off > 0; off >>= 1) m = fmaxf(m, __shfl_xor(m, off));
      float p = __expf(v - m);
      float su = p;
      #pragma unroll
      for (int off = 32; off > 0; off >>= 1) su += __shfl_xor(su, off);
      al_s[s][lane] = p * __builtin_amdgcn_rcpf(su);
    }
    __syncthreads();                   // B7: al ready

    // ---- pre, both batches: alpha@Vl (4-way tq split) + hwg + x + bias
    #pragma unroll
    for (int s = 0; s < 2; ++s) {
      float d0 = 0.f, d1 = 0.f;
      #pragma unroll
      for (int i = 0; i < 8; ++i) {
        int tw = gq * 8 + i;
        unsigned int v = vl_l[s][i][tid];
        d0 = fmaf(al_s[s][2 * tw], bflo(v), d0);
        d1 = fmaf(al_s[s][2 * tw + 1], bfhi(v), d1);
      }
      float d = d0 + d1;
      d += __shfl_xor(d, 1);
      d += __shfl_xor(d, 2);
      if (gq == 0)
        pre_s[s][gcol] = (s ? hwgB : hwgA) + d + xsl[s][32 + gcol] + bias_s[gcol];
    }
    __syncthreads();                   // B8: pre ready

    // ---- gates + state: wave 0, lanes 0-31 batch A, lanes 32-63 batch B
    if (tid < 64) {
      int s = lane >> 5, e = lane & 31;
      float f  = pre_s[s][e];
      float ii = pre_s[s][32 + e];
      float oo = pre_s[s][64 + e];
      float g  = pre_s[s][96 + e];
      int m = (j << 5) + e;
      float c0 = cv, h0 = h_lds[s][m];
      float c1 = fast_sigmoid(f) * c0 + fast_sigmoid(ii) * fast_tanh(g);
      c1 = c1 * mtv + c0 * (1.f - mtv);
      float h1 = fast_sigmoid(oo) * fast_tanh(c1);
      h1 = h1 * mtv + h0 * (1.f - mtv);
      cv = c1;
      astore64(xh[s] + m, packsv(h1, sseq));
      out[((size_t)(s ? bS1 : bS0) * TPL + t) * DD + m] = h1;
    }
    // no trailing barrier: next iteration's B0 orders h_lds reuse
  }
  (void)c_dummy;
}

// -----------------------------------------------------------------------------
extern "C" void kernel_launch(void* const* d_in, const int* in_sizes, int n_in,
                              void* d_out, int out_size, void* d_ws, size_t ws_size,
                              hipStream_t stream) {
  const float* input_p  = (const float*)d_in[0];
  const float* mask_p   = (const float*)d_in[1];
  const float* input_q  = (const float*)d_in[2];
  const float* mask_q   = (const float*)d_in[3];
  const float* W_att_p  = (const float*)d_in[4];
  const float* W_att_q  = (const float*)d_in[5];
  const float* W_att_r  = (const float*)d_in[6];
  const float* w_att    = (const float*)d_in[7];
  const float* W_lstm   = (const float*)d_in[8];
  const float* bias_f   = (const float*)d_in[9];
  const float* bias_iog = (const float*)d_in[10];
  float* out = (float*)d_out;
  float* ws  = (float*)d_ws;
  (void)ws_size; (void)in_sizes; (void)n_in; (void)out_size;

  const size_t SZ_XPL  = (size_t)NB * TPL * NC;
  const size_t SZ_QV   = (size_t)NB * TQL * NC;
  const size_t SZ_W    = (size_t)DD * NC;
  const size_t SZ_ATTL = (size_t)NS * 4 * 512;    // uint2 per layer
  const size_t SZ_GATL = (size_t)NS * 16 * 512;   // uint2 per layer

  float* ws_xpl = ws;
  float* ws_qv  = ws_xpl + SZ_XPL;
  float* ws_wx  = ws_qv  + 2 * SZ_QV;
  float* ws_wqv = ws_wx  + 2 * SZ_W;
  float* ws_o0  = ws_wqv + 2 * SZ_W;
  uint2* ws_attl = (uint2*)(ws_o0 + (size_t)NB * TPL * DD);
  uint2* ws_gatl = ws_attl + 2 * SZ_ATTL;
  u64*   ws_xs   = (u64*)(ws_gatl + 2 * SZ_GATL);    // [NB][8][64] seq-stamped
  u64*   ws_xh   = ws_xs + NB * NS * TQL;            // [NB][256]  seq-stamped

  dim3 gpack((DD * NC + 255) / 256, 2);
  pack_weights<<<gpack, 256, 0, stream>>>(W_att_p, W_att_q, W_lstm, ws_wx, ws_wqv);
  pack_attl<<<(2 * NS * 4 * 512 + 255) / 256, 256, 0, stream>>>(W_att_r, ws_attl);
  pack_gatel<<<(2 * NS * 16 * 512 + 255) / 256, 256, 0, stream>>>(W_lstm, ws_gatl);
  hipMemsetAsync(ws_xs, 0, (NB * NS * TQL + NB * DD) * sizeof(u64), stream);

  for (int d = 0; d < 2; ++d) {
    dim3 g(NC / 64, (NB * TQL) / 64);
    sgemm<false><<<g, 256, 0, stream>>>(input_q, ws_wqv + d * SZ_W, ws_qv + d * SZ_QV);
  }

  // layer 0
  {
    dim3 g(NC / 64, (NB * TPL) / 64);
    sgemm<true><<<g, 256, 0, stream>>>(input_p, ws_wx, ws_xpl);
    scan<<<NB * NS / 2, 512, 0, stream>>>(ws_xpl, ws_qv, ws_attl, ws_gatl,
                                          w_att, bias_f, bias_iog, mask_p, mask_q,
                                          ws_xs, ws_xh, ws_o0, 0);
  }
  // layer 1
  {
    dim3 g(NC / 64, (NB * TPL) / 64);
    sgemm<true><<<g, 256, 0, stream>>>(ws_o0, ws_wx + SZ_W, ws_xpl);
    scan<<<NB * NS / 2, 512, 0, stream>>>(ws_xpl, ws_qv + SZ_QV, ws_attl + SZ_ATTL,
                                          ws_gatl + SZ_GATL, w_att + DD, bias_f + DD,
                                          bias_iog + 3 * DD, mask_p, mask_q,
                                          ws_xs, ws_xh, out, TPL);
  }
}